// Round 6
// baseline (175.667 us; speedup 1.0000x reference)
//
#include <hip/hip_runtime.h>
#include <hip/hip_bf16.h>
#include <stdint.h>

typedef __bf16 bf16x8 __attribute__((ext_vector_type(8)));
typedef float  f32x4  __attribute__((ext_vector_type(4)));

constexpr int Bb = 4;      // batch
constexpr int Tt = 1024;   // tokens
constexpr int Cc = 1024;   // channels
constexpr int Kk = 16;     // sparse K
constexpr int HK = 256;    // heads*keys

__device__ inline __bf16 f2bf(float f) {
    union { __hip_bfloat16 h; __bf16 b; } u;
    u.h = __float2bfloat16(f);
    return u.b;
}

__device__ inline void load_lds16(const __hip_bfloat16* g, __hip_bfloat16* l) {
    auto gp = (const __attribute__((address_space(1))) unsigned int*)(uintptr_t)g;
    auto lp = (__attribute__((address_space(3))) unsigned int*)(uintptr_t)l;
    __builtin_amdgcn_global_load_lds(gp, lp, 16, 0, 0);
}

__global__ __launch_bounds__(256)
void cvt_f32_bf16(const float* __restrict__ src, __hip_bfloat16* __restrict__ dst, int n)
{
    int i = (blockIdx.x * 256 + threadIdx.x) * 8;
    if (i >= n) return;
    float4 a = *reinterpret_cast<const float4*>(src + i);
    float4 b = *reinterpret_cast<const float4*>(src + i + 4);
    bf16x8 v;
    v[0] = f2bf(a.x); v[1] = f2bf(a.y); v[2] = f2bf(a.z); v[3] = f2bf(a.w);
    v[4] = f2bf(b.x); v[5] = f2bf(b.y); v[6] = f2bf(b.z); v[7] = f2bf(b.w);
    *reinterpret_cast<bf16x8*>(dst + i) = v;
}

// C[M,N] = A[M,K] @ B[N,K]^T, bf16 in, fp32 accum. Batched via blockIdx.z with
// element strides sA/sB/sC. GATHER: A row m -> x row (m>>4)*Tt + (m&15).
// Block 256 = 4 waves (2x2); frags 16x16x32; LDS via global_load_lds w16; BK=32.
template<int BM, int BN, bool GATHER, bool OUT_BF16>
__global__ __launch_bounds__(256)
void gemm_mfma(const __hip_bfloat16* __restrict__ A,
               const __hip_bfloat16* __restrict__ Bm,
               void* __restrict__ Cout, int M, int N, int K,
               size_t sA, size_t sB, size_t sC)
{
    constexpr int FI = BM / 32;
    constexpr int FJ = BN / 32;
    __shared__ __hip_bfloat16 smem[(BM + BN) * 32];
    __hip_bfloat16* As = smem;
    __hip_bfloat16* Bs = smem + BM * 32;

    A += (size_t)blockIdx.z * sA;
    Bm += (size_t)blockIdx.z * sB;

    const int lane = threadIdx.x & 63;
    const int wave = threadIdx.x >> 6;
    const int wm = wave >> 1, wn = wave & 1;
    const int tileM = blockIdx.y * BM;
    const int tileN = blockIdx.x * BN;
    const int r16 = lane & 15;
    const int kq  = (lane >> 4) * 8;

    f32x4 acc[FI][FJ] = {};

    for (int kk = 0; kk < K; kk += 32) {
#pragma unroll
        for (int t = 0; t < BM / 64; ++t) {
            int g = (wave * (BM / 64) + t) * 64 + lane;
            int r = g >> 2;
            int col = (g & 3) * 8;
            int am = tileM + r;
            size_t grow = GATHER ? ((size_t)(am >> 4) * Tt + (am & 15)) : (size_t)am;
            load_lds16(A + grow * (size_t)K + kk + col,
                       As + (size_t)(wave * (BM / 64) + t) * 512);
        }
#pragma unroll
        for (int t = 0; t < BN / 64; ++t) {
            int g = (wave * (BN / 64) + t) * 64 + lane;
            int r = g >> 2;
            int col = (g & 3) * 8;
            load_lds16(Bm + (size_t)(tileN + r) * K + kk + col,
                       Bs + (size_t)(wave * (BN / 64) + t) * 512);
        }
        __syncthreads();

        bf16x8 a[FI], b[FJ];
#pragma unroll
        for (int i = 0; i < FI; ++i)
            a[i] = *reinterpret_cast<const bf16x8*>(
                As + (size_t)(wm * (BM / 2) + i * 16 + r16) * 32 + kq);
#pragma unroll
        for (int j = 0; j < FJ; ++j)
            b[j] = *reinterpret_cast<const bf16x8*>(
                Bs + (size_t)(wn * (BN / 2) + j * 16 + r16) * 32 + kq);
#pragma unroll
        for (int i = 0; i < FI; ++i)
#pragma unroll
            for (int j = 0; j < FJ; ++j)
                acc[i][j] = __builtin_amdgcn_mfma_f32_16x16x32_bf16(a[i], b[j], acc[i][j], 0, 0, 0);
        __syncthreads();
    }

    const int crow0 = (lane >> 4) * 4;
    const int ccol  = lane & 15;
#pragma unroll
    for (int i = 0; i < FI; ++i)
#pragma unroll
        for (int j = 0; j < FJ; ++j)
#pragma unroll
            for (int r = 0; r < 4; ++r) {
                size_t row = tileM + wm * (BM / 2) + i * 16 + crow0 + r;
                size_t col = tileN + wn * (BN / 2) + j * 16 + ccol;
                float v = acc[i][j][r];
                if (OUT_BF16)
                    ((__hip_bfloat16*)Cout)[(size_t)blockIdx.z * sC + row * N + col] = __float2bfloat16(v);
                else
                    ((float*)Cout)[(size_t)blockIdx.z * sC + row * N + col] = v;
            }
}

// Precompute QK[b][h*16+k][c] = sum_d k_sel[b,h,k,d] * Wq[h*64+d, c]   (type 0)
//        and vPt[b][c][h*16+k] = sum_d v_sel[b,h,k,d] * W_proj[c, h*64+d] (type 1)
// kv fp32 [64][2048] (K cols 0..1023, V cols 1024..2047). 128 blocks.
__global__ __launch_bounds__(256)
void precompute(const float* __restrict__ kv,
                const float* __restrict__ W_attn,   // rows 0..1023 = Wq
                const float* __restrict__ W_proj,
                __hip_bfloat16* __restrict__ QKb,   // [Bb][256][1024]
                __hip_bfloat16* __restrict__ vPt)   // [Bb][1024][256]
{
    __shared__ float sel[Kk][64];
    const int type = blockIdx.x >> 6;
    const int bh = blockIdx.x & 63;
    const int b = bh >> 4, h = bh & 15;
    const int tid = threadIdx.x;

    for (int e = tid; e < Kk * 64; e += 256) {
        int slot = e >> 6, d = e & 63;
        sel[slot][d] = kv[(size_t)(b * Kk + slot) * 2048 + type * 1024 + h * 64 + d];
    }
    __syncthreads();

    if (type == 0) {
        for (int cc = 0; cc < 4; ++cc) {
            int c = cc * 256 + tid;
            float acc[Kk] = {};
            for (int d = 0; d < 64; ++d) {
                float wv = W_attn[(size_t)(h * 64 + d) * 1024 + c];
#pragma unroll
                for (int k = 0; k < Kk; ++k) acc[k] += wv * sel[k][d];
            }
#pragma unroll
            for (int k = 0; k < Kk; ++k)
                QKb[((size_t)b * HK + h * 16 + k) * 1024 + c] = __float2bfloat16(acc[k]);
        }
    } else {
        for (int cc = 0; cc < 4; ++cc) {
            int c = cc * 256 + tid;
            float acc[Kk] = {};
            const float* wrow = W_proj + (size_t)c * 1024 + h * 64;
            for (int d = 0; d < 64; d += 4) {
                float4 wv = *reinterpret_cast<const float4*>(wrow + d);
#pragma unroll
                for (int k = 0; k < Kk; ++k)
                    acc[k] += wv.x * sel[k][d] + wv.y * sel[k][d + 1]
                            + wv.z * sel[k][d + 2] + wv.w * sel[k][d + 3];
            }
            bf16x8 p0, p1;
#pragma unroll
            for (int k = 0; k < 8; ++k) { p0[k] = f2bf(acc[k]); p1[k] = f2bf(acc[k + 8]); }
            __hip_bfloat16* dst = vPt + ((size_t)b * 1024 + c) * HK + h * 16;
            *reinterpret_cast<bf16x8*>(dst) = p0;
            *reinterpret_cast<bf16x8*>(dst + 8) = p1;
        }
    }
}

// logits[b][t][hk] = 0.125 * x[b,t,:]·QK[b,hk,:], then per-(t,h) softmax over
// the 16 k (mask k<=t) fused in the epilogue via 16-lane shfl reductions.
// BM=BN=64, grid (4, 16, Bb). Writes w bf16 [Bb][1024][256].
__global__ __launch_bounds__(256)
void logits_softmax(const __hip_bfloat16* __restrict__ xb,
                    const __hip_bfloat16* __restrict__ QKb,
                    __hip_bfloat16* __restrict__ wout)
{
    constexpr int BM = 64, BN = 64, FI = 2, FJ = 2;
    __shared__ __hip_bfloat16 smem[(BM + BN) * 32];
    __hip_bfloat16* As = smem;
    __hip_bfloat16* Bs = smem + BM * 32;

    const __hip_bfloat16* A = xb + (size_t)blockIdx.z * Tt * Cc;
    const __hip_bfloat16* Bm = QKb + (size_t)blockIdx.z * HK * Cc;

    const int lane = threadIdx.x & 63;
    const int wave = threadIdx.x >> 6;
    const int wm = wave >> 1, wn = wave & 1;
    const int tileM = blockIdx.y * BM;
    const int tileN = blockIdx.x * BN;
    const int r16 = lane & 15;
    const int kq  = (lane >> 4) * 8;

    f32x4 acc[FI][FJ] = {};
    for (int kk = 0; kk < Cc; kk += 32) {
        {
            int g = wave * 64 + lane;
            load_lds16(A + (size_t)(tileM + (g >> 2)) * Cc + kk + (g & 3) * 8,
                       As + (size_t)wave * 512);
            load_lds16(Bm + (size_t)(tileN + (g >> 2)) * Cc + kk + (g & 3) * 8,
                       Bs + (size_t)wave * 512);
        }
        __syncthreads();
        bf16x8 a[FI], b[FJ];
#pragma unroll
        for (int i = 0; i < FI; ++i)
            a[i] = *reinterpret_cast<const bf16x8*>(As + (size_t)(wm * 32 + i * 16 + r16) * 32 + kq);
#pragma unroll
        for (int j = 0; j < FJ; ++j)
            b[j] = *reinterpret_cast<const bf16x8*>(Bs + (size_t)(wn * 32 + j * 16 + r16) * 32 + kq);
#pragma unroll
        for (int i = 0; i < FI; ++i)
#pragma unroll
            for (int j = 0; j < FJ; ++j)
                acc[i][j] = __builtin_amdgcn_mfma_f32_16x16x32_bf16(a[i], b[j], acc[i][j], 0, 0, 0);
        __syncthreads();
    }

    const int crow0 = (lane >> 4) * 4;
    const int ccol  = lane & 15;        // == k index within the head
#pragma unroll
    for (int i = 0; i < FI; ++i)
#pragma unroll
        for (int r = 0; r < 4; ++r) {
            int t = tileM + wm * 32 + i * 16 + crow0 + r;   // token within batch
            bool valid = (ccol <= t);
#pragma unroll
            for (int j = 0; j < FJ; ++j) {
                int hk = tileN + wn * 32 + j * 16 + ccol;
                float v = acc[i][j][r] * 0.125f;
                float vm = valid ? v : -3.0e38f;
#pragma unroll
                for (int m = 1; m < 16; m <<= 1) vm = fmaxf(vm, __shfl_xor(vm, m));
                float e = valid ? __expf(v - vm) : 0.f;
                float s = e;
#pragma unroll
                for (int m = 1; m < 16; m <<= 1) s += __shfl_xor(s, m);
                wout[((size_t)blockIdx.z * Tt + t) * HK + hk] = __float2bfloat16(e / s);
            }
        }
}

extern "C" void kernel_launch(void* const* d_in, const int* in_sizes, int n_in,
                              void* d_out, int out_size, void* d_ws, size_t ws_size,
                              hipStream_t stream)
{
    (void)in_sizes; (void)n_in; (void)out_size; (void)ws_size;
    const float* x      = (const float*)d_in[0];
    const float* W_attn = (const float*)d_in[1];
    const float* W_proj = (const float*)d_in[2];
    // d_in[3] = W_rel dead (round-4 verified): top_k values discarded; only
    // finite score at col 0 -> idx = [0..15] for every (h,t).
    float* out = (float*)d_out;

    char* ws = (char*)d_ws;
    float*          kv_ws = (float*)ws;                                     // 512 KB fp32 [64][2048]
    __hip_bfloat16* xb    = (__hip_bfloat16*)(ws + (1u << 20));             // 8 MB
    __hip_bfloat16* Wkvb  = (__hip_bfloat16*)(ws + (9u << 20));             // 4 MB (Wk|Wv bf16)
    __hip_bfloat16* QKb   = (__hip_bfloat16*)(ws + (13u << 20));            // 2 MB [4][256][1024]
    __hip_bfloat16* vPt   = (__hip_bfloat16*)(ws + (15u << 20));            // 2 MB [4][1024][256]
    __hip_bfloat16* w_ws  = (__hip_bfloat16*)(ws + (17u << 20));            // 2 MB [4][1024][256]

    // 1-2) fp32 -> bf16: x (4M elems), Wk|Wv (2M elems).
    cvt_f32_bf16<<<2048, 256, 0, stream>>>(x, xb, Bb * Tt * Cc);
    cvt_f32_bf16<<<1024, 256, 0, stream>>>(W_attn + (size_t)Cc * Cc, Wkvb, 2 * Cc * Cc);
    // 3) K/V for tokens 0..15 per batch: M=64 (gathered), N=2048, fp32 out.
    gemm_mfma<64, 64, true, false><<<dim3(32, 1, 1), 256, 0, stream>>>(
        xb, Wkvb, kv_ws, 64, 2048, Cc, 0, 0, 0);
    // 4) QK / vPt precompute (fp32 math, bf16 out). 128 blocks.
    precompute<<<128, 256, 0, stream>>>(kv_ws, W_attn, W_proj, QKb, vPt);
    // 5) logits GEMM + fused masked softmax -> w.
    logits_softmax<<<dim3(HK / 64, Tt / 64, Bb), 256, 0, stream>>>(xb, QKb, w_ws);
    // 6) out[b] = w[b] @ vPt[b]^T  (M=1024, N=1024, K=256), fp32 -> d_out.
    gemm_mfma<128, 64, false, false><<<dim3(Cc / 64, Tt / 128, Bb), 256, 0, stream>>>(
        w_ws, vPt, out, Tt, Cc, HK,
        (size_t)Tt * HK, (size_t)Cc * HK, (size_t)Tt * Cc);
}

// Round 7
// 131.297 us; speedup vs baseline: 1.3379x; 1.3379x over previous
//
#include <hip/hip_runtime.h>
#include <hip/hip_bf16.h>
#include <stdint.h>

typedef __bf16 bf16x8 __attribute__((ext_vector_type(8)));
typedef float  f32x4  __attribute__((ext_vector_type(4)));

constexpr int Bb = 4;      // batch
constexpr int Tt = 1024;   // tokens
constexpr int Cc = 1024;   // channels
constexpr int Kk = 16;     // sparse K
constexpr int HK = 256;    // heads*keys

__device__ inline __bf16 f2bf(float f) {
    union { __hip_bfloat16 h; __bf16 b; } u;
    u.h = __float2bfloat16(f);
    return u.b;
}

__device__ inline void load_lds16(const __hip_bfloat16* g, __hip_bfloat16* l) {
    auto gp = (const __attribute__((address_space(1))) unsigned int*)(uintptr_t)g;
    auto lp = (__attribute__((address_space(3))) unsigned int*)(uintptr_t)l;
    __builtin_amdgcn_global_load_lds(gp, lp, 16, 0, 0);
}

// Merged fp32->bf16: blocks [0,2048) convert x (4M elems), [2048,3072) Wkv (2M).
__global__ __launch_bounds__(256)
void cvt_all(const float* __restrict__ x, const float* __restrict__ Wkv,
             __hip_bfloat16* __restrict__ xb, __hip_bfloat16* __restrict__ Wkvb)
{
    const float* src; __hip_bfloat16* dst; int i;
    if (blockIdx.x < 2048) { src = x;   dst = xb;   i = (blockIdx.x * 256 + threadIdx.x) * 8; }
    else                   { src = Wkv; dst = Wkvb; i = ((blockIdx.x - 2048) * 256 + threadIdx.x) * 8; }
    float4 a = *reinterpret_cast<const float4*>(src + i);
    float4 b = *reinterpret_cast<const float4*>(src + i + 4);
    bf16x8 v;
    v[0] = f2bf(a.x); v[1] = f2bf(a.y); v[2] = f2bf(a.z); v[3] = f2bf(a.w);
    v[4] = f2bf(b.x); v[5] = f2bf(b.y); v[6] = f2bf(b.z); v[7] = f2bf(b.w);
    *reinterpret_cast<bf16x8*>(dst + i) = v;
}

// C[M,N] = A[M,K] @ B[N,K]^T, bf16 in, fp32 accum. Batched via blockIdx.z.
// GATHER: A row m -> x row (m>>4)*Tt + (m&15). Block 256 = 4 waves (2x2).
template<int BM, int BN, bool GATHER, bool OUT_BF16>
__global__ __launch_bounds__(256)
void gemm_mfma(const __hip_bfloat16* __restrict__ A,
               const __hip_bfloat16* __restrict__ Bm,
               void* __restrict__ Cout, int M, int N, int K,
               size_t sA, size_t sB, size_t sC)
{
    constexpr int FI = BM / 32;
    constexpr int FJ = BN / 32;
    __shared__ __hip_bfloat16 smem[(BM + BN) * 32];
    __hip_bfloat16* As = smem;
    __hip_bfloat16* Bs = smem + BM * 32;

    A += (size_t)blockIdx.z * sA;
    Bm += (size_t)blockIdx.z * sB;

    const int lane = threadIdx.x & 63;
    const int wave = threadIdx.x >> 6;
    const int wm = wave >> 1, wn = wave & 1;
    const int tileM = blockIdx.y * BM;
    const int tileN = blockIdx.x * BN;
    const int r16 = lane & 15;
    const int kq  = (lane >> 4) * 8;

    f32x4 acc[FI][FJ] = {};

    for (int kk = 0; kk < K; kk += 32) {
#pragma unroll
        for (int t = 0; t < BM / 64; ++t) {
            int g = (wave * (BM / 64) + t) * 64 + lane;
            int r = g >> 2;
            int col = (g & 3) * 8;
            int am = tileM + r;
            size_t grow = GATHER ? ((size_t)(am >> 4) * Tt + (am & 15)) : (size_t)am;
            load_lds16(A + grow * (size_t)K + kk + col,
                       As + (size_t)(wave * (BM / 64) + t) * 512);
        }
#pragma unroll
        for (int t = 0; t < BN / 64; ++t) {
            int g = (wave * (BN / 64) + t) * 64 + lane;
            int r = g >> 2;
            int col = (g & 3) * 8;
            load_lds16(Bm + (size_t)(tileN + r) * K + kk + col,
                       Bs + (size_t)(wave * (BN / 64) + t) * 512);
        }
        __syncthreads();

        bf16x8 a[FI], b[FJ];
#pragma unroll
        for (int i = 0; i < FI; ++i)
            a[i] = *reinterpret_cast<const bf16x8*>(
                As + (size_t)(wm * (BM / 2) + i * 16 + r16) * 32 + kq);
#pragma unroll
        for (int j = 0; j < FJ; ++j)
            b[j] = *reinterpret_cast<const bf16x8*>(
                Bs + (size_t)(wn * (BN / 2) + j * 16 + r16) * 32 + kq);
#pragma unroll
        for (int i = 0; i < FI; ++i)
#pragma unroll
            for (int j = 0; j < FJ; ++j)
                acc[i][j] = __builtin_amdgcn_mfma_f32_16x16x32_bf16(a[i], b[j], acc[i][j], 0, 0, 0);
        __syncthreads();
    }

    const int crow0 = (lane >> 4) * 4;
    const int ccol  = lane & 15;
#pragma unroll
    for (int i = 0; i < FI; ++i)
#pragma unroll
        for (int j = 0; j < FJ; ++j)
#pragma unroll
            for (int r = 0; r < 4; ++r) {
                size_t row = tileM + wm * (BM / 2) + i * 16 + crow0 + r;
                size_t col = tileN + wn * (BN / 2) + j * 16 + ccol;
                float v = acc[i][j][r];
                if (OUT_BF16)
                    ((__hip_bfloat16*)Cout)[(size_t)blockIdx.z * sC + row * N + col] = __float2bfloat16(v);
                else
                    ((float*)Cout)[(size_t)blockIdx.z * sC + row * N + col] = v;
            }
}

// QK[b][h*16+k][c] = sum_d k_sel[b,h,k,d] * Wq[h*64+d, c]        (type 0)
// vPt[b][c][h*16+k] = sum_d v_sel[b,h,k,d] * W_proj[c, h*64+d]   (type 1)
// Grid 512 = 2 types x 64 (b,h) x 4 c-chunks; thread owns one c, all 16 k.
// sel in LDS [d][16] so the k-vector reads are 4x float4 broadcasts (free).
__global__ __launch_bounds__(256)
void precompute(const float* __restrict__ kv,     // fp32 [64][2048]
                const float* __restrict__ W_attn, // rows 0..1023 = Wq
                const float* __restrict__ W_proj,
                __hip_bfloat16* __restrict__ QKb,  // [Bb][256][1024]
                __hip_bfloat16* __restrict__ vPt)  // [Bb][1024][256]
{
    __shared__ float sel[64][16];   // [d][k]
    const int blk = blockIdx.x;
    const int type = blk >> 8;
    const int bh = (blk >> 2) & 63;
    const int cchunk = blk & 3;
    const int b = bh >> 4, h = bh & 15;
    const int tid = threadIdx.x;

    for (int e = tid; e < Kk * 64; e += 256) {
        int k = e >> 6, d = e & 63;
        sel[d][k] = kv[(size_t)(b * Kk + k) * 2048 + type * 1024 + h * 64 + d];
    }
    __syncthreads();

    const int c = cchunk * 256 + tid;
    float acc[Kk] = {};

    if (type == 0) {
        const float* wp = W_attn + (size_t)(h * 64) * 1024 + c;
#pragma unroll 4
        for (int d = 0; d < 64; ++d) {
            float wv = wp[(size_t)d * 1024];
            const float4* sv = reinterpret_cast<const float4*>(sel[d]);
            float4 s0 = sv[0], s1 = sv[1], s2 = sv[2], s3 = sv[3];
            acc[0]  += wv * s0.x; acc[1]  += wv * s0.y; acc[2]  += wv * s0.z; acc[3]  += wv * s0.w;
            acc[4]  += wv * s1.x; acc[5]  += wv * s1.y; acc[6]  += wv * s1.z; acc[7]  += wv * s1.w;
            acc[8]  += wv * s2.x; acc[9]  += wv * s2.y; acc[10] += wv * s2.z; acc[11] += wv * s2.w;
            acc[12] += wv * s3.x; acc[13] += wv * s3.y; acc[14] += wv * s3.z; acc[15] += wv * s3.w;
        }
#pragma unroll
        for (int k = 0; k < Kk; ++k)
            QKb[((size_t)b * HK + h * 16 + k) * 1024 + c] = __float2bfloat16(acc[k]);
    } else {
        const float* wrow = W_proj + (size_t)c * 1024 + h * 64;
#pragma unroll 4
        for (int d4 = 0; d4 < 64; d4 += 4) {
            float4 wv = *reinterpret_cast<const float4*>(wrow + d4);
            const float w4[4] = {wv.x, wv.y, wv.z, wv.w};
#pragma unroll
            for (int dd = 0; dd < 4; ++dd) {
                float wvv = w4[dd];
                const float4* sv = reinterpret_cast<const float4*>(sel[d4 + dd]);
                float4 s0 = sv[0], s1 = sv[1], s2 = sv[2], s3 = sv[3];
                acc[0]  += wvv * s0.x; acc[1]  += wvv * s0.y; acc[2]  += wvv * s0.z; acc[3]  += wvv * s0.w;
                acc[4]  += wvv * s1.x; acc[5]  += wvv * s1.y; acc[6]  += wvv * s1.z; acc[7]  += wvv * s1.w;
                acc[8]  += wvv * s2.x; acc[9]  += wvv * s2.y; acc[10] += wvv * s2.z; acc[11] += wvv * s2.w;
                acc[12] += wvv * s3.x; acc[13] += wvv * s3.y; acc[14] += wvv * s3.z; acc[15] += wvv * s3.w;
            }
        }
        bf16x8 p0, p1;
#pragma unroll
        for (int k = 0; k < 8; ++k) { p0[k] = f2bf(acc[k]); p1[k] = f2bf(acc[k + 8]); }
        __hip_bfloat16* dst = vPt + ((size_t)b * 1024 + c) * HK + h * 16;
        *reinterpret_cast<bf16x8*>(dst) = p0;
        *reinterpret_cast<bf16x8*>(dst + 8) = p1;
    }
}

// logits[b][t][hk] = 0.125 * x[b,t,:]·QK[b,hk,:] with fused per-(t,h) masked
// softmax over 16 keys (16-lane shfl reductions). Writes w bf16 [Bb][1024][256].
__global__ __launch_bounds__(256)
void logits_softmax(const __hip_bfloat16* __restrict__ xb,
                    const __hip_bfloat16* __restrict__ QKb,
                    __hip_bfloat16* __restrict__ wout)
{
    constexpr int BM = 64, BN = 64, FI = 2, FJ = 2;
    __shared__ __hip_bfloat16 smem[(BM + BN) * 32];
    __hip_bfloat16* As = smem;
    __hip_bfloat16* Bs = smem + BM * 32;

    const __hip_bfloat16* A = xb + (size_t)blockIdx.z * Tt * Cc;
    const __hip_bfloat16* Bm = QKb + (size_t)blockIdx.z * HK * Cc;

    const int lane = threadIdx.x & 63;
    const int wave = threadIdx.x >> 6;
    const int wm = wave >> 1, wn = wave & 1;
    const int tileM = blockIdx.y * BM;
    const int tileN = blockIdx.x * BN;
    const int r16 = lane & 15;
    const int kq  = (lane >> 4) * 8;

    f32x4 acc[FI][FJ] = {};
    for (int kk = 0; kk < Cc; kk += 32) {
        {
            int g = wave * 64 + lane;
            load_lds16(A + (size_t)(tileM + (g >> 2)) * Cc + kk + (g & 3) * 8,
                       As + (size_t)wave * 512);
            load_lds16(Bm + (size_t)(tileN + (g >> 2)) * Cc + kk + (g & 3) * 8,
                       Bs + (size_t)wave * 512);
        }
        __syncthreads();
        bf16x8 a[FI], b[FJ];
#pragma unroll
        for (int i = 0; i < FI; ++i)
            a[i] = *reinterpret_cast<const bf16x8*>(As + (size_t)(wm * 32 + i * 16 + r16) * 32 + kq);
#pragma unroll
        for (int j = 0; j < FJ; ++j)
            b[j] = *reinterpret_cast<const bf16x8*>(Bs + (size_t)(wn * 32 + j * 16 + r16) * 32 + kq);
#pragma unroll
        for (int i = 0; i < FI; ++i)
#pragma unroll
            for (int j = 0; j < FJ; ++j)
                acc[i][j] = __builtin_amdgcn_mfma_f32_16x16x32_bf16(a[i], b[j], acc[i][j], 0, 0, 0);
        __syncthreads();
    }

    const int crow0 = (lane >> 4) * 4;
    const int ccol  = lane & 15;        // == k index within the head
#pragma unroll
    for (int i = 0; i < FI; ++i)
#pragma unroll
        for (int r = 0; r < 4; ++r) {
            int t = tileM + wm * 32 + i * 16 + crow0 + r;
            bool valid = (ccol <= t);
#pragma unroll
            for (int j = 0; j < FJ; ++j) {
                int hk = tileN + wn * 32 + j * 16 + ccol;
                float v = acc[i][j][r] * 0.125f;
                float vm = valid ? v : -3.0e38f;
#pragma unroll
                for (int m = 1; m < 16; m <<= 1) vm = fmaxf(vm, __shfl_xor(vm, m));
                float e = valid ? __expf(v - vm) : 0.f;
                float s = e;
#pragma unroll
                for (int m = 1; m < 16; m <<= 1) s += __shfl_xor(s, m);
                wout[((size_t)blockIdx.z * Tt + t) * HK + hk] = __float2bfloat16(e / s);
            }
        }
}

extern "C" void kernel_launch(void* const* d_in, const int* in_sizes, int n_in,
                              void* d_out, int out_size, void* d_ws, size_t ws_size,
                              hipStream_t stream)
{
    (void)in_sizes; (void)n_in; (void)out_size; (void)ws_size;
    const float* x      = (const float*)d_in[0];
    const float* W_attn = (const float*)d_in[1];
    const float* W_proj = (const float*)d_in[2];
    // d_in[3] = W_rel dead (round-4 verified): top_k values discarded; only
    // finite score at col 0 -> idx = [0..15] for every (h,t).
    float* out = (float*)d_out;

    char* ws = (char*)d_ws;
    float*          kv_ws = (float*)ws;                          // 512 KB fp32 [64][2048]
    __hip_bfloat16* xb    = (__hip_bfloat16*)(ws + (1u << 20));  // 8 MB
    __hip_bfloat16* Wkvb  = (__hip_bfloat16*)(ws + (9u << 20));  // 4 MB (Wk|Wv)
    __hip_bfloat16* QKb   = (__hip_bfloat16*)(ws + (13u << 20)); // 2 MB [4][256][1024]
    __hip_bfloat16* vPt   = (__hip_bfloat16*)(ws + (15u << 20)); // 2 MB [4][1024][256]
    __hip_bfloat16* w_ws  = (__hip_bfloat16*)(ws + (17u << 20)); // 2 MB [4][1024][256]

    // 1) fp32 -> bf16 (x and Wk|Wv in one launch).
    cvt_all<<<3072, 256, 0, stream>>>(x, W_attn + (size_t)Cc * Cc, xb, Wkvb);
    // 2) K/V for tokens 0..15 per batch: M=64 (gathered), N=2048, fp32 out.
    gemm_mfma<64, 64, true, false><<<dim3(32, 1, 1), 256, 0, stream>>>(
        xb, Wkvb, kv_ws, 64, 2048, Cc, 0, 0, 0);
    // 3) QK / vPt precompute (fp32 math, bf16 out). 512 blocks.
    precompute<<<512, 256, 0, stream>>>(kv_ws, W_attn, W_proj, QKb, vPt);
    // 4) logits GEMM + fused masked softmax -> w.
    logits_softmax<<<dim3(HK / 64, Tt / 64, Bb), 256, 0, stream>>>(xb, QKb, w_ws);
    // 5) out[b] = w[b] @ vPt[b]^T  (M=1024, N=1024, K=256), fp32 -> d_out.
    gemm_mfma<128, 64, false, false><<<dim3(Cc / 64, Tt / 128, Bb), 256, 0, stream>>>(
        w_ws, vPt, out, Tt, Cc, HK,
        (size_t)Tt * HK, (size_t)Cc * HK, (size_t)Tt * Cc);
}